// Round 12
// baseline (66.325 us; speedup 1.0000x reference)
//
#include <hip/hip_runtime.h>
#include <hip/hip_bf16.h>
#include <math.h>

#define BB 8
#define SS 512
#define EE 128
#define HH 16
#define DKK 8

#define FMA4(ACC, S, W) do { (ACC).x += (S)*(W).x; (ACC).y += (S)*(W).y; \
                             (ACC).z += (S)*(W).z; (ACC).w += (S)*(W).w; } while(0)
#define ADD4(A, B) do { (A).x += (B).x; (A).y += (B).y; (A).z += (B).z; (A).w += (B).w; } while(0)
#define DOT4(A, B) ((A).x*(B).x + (A).y*(B).y + (A).z*(B).z + (A).w*(B).w)

// ---------------------------------------------------------------------------
// Kernel 1: QKV GEMM + bias + theta + quantum head (R9-proven).
// grid (256, 3); block 256 = 4 waves; per-lane tile 2 rows x 4 cols.
// x tile staged in LDS (8KB, broadcast b128 reads); W coalesced float4.
// Output layout (B, H, S, 8).
// ---------------------------------------------------------------------------
__global__ __launch_bounds__(256, 4) void k_qkvq(
    const float* __restrict__ x,
    const float* __restrict__ Wq, const float* __restrict__ bq,
    const float* __restrict__ Wk, const float* __restrict__ bk,
    const float* __restrict__ Wv, const float* __restrict__ bv,
    const float* __restrict__ theta,
    float* __restrict__ qh, float* __restrict__ kh, float* __restrict__ vh)
{
    __shared__ float xs[16][128];
    const int t = threadIdx.x;
    const int m = blockIdx.y;
    const int row0 = blockIdx.x * 16;

    {
        const float4* xv = (const float4*)(x + (size_t)row0 * 128);
        float4* xsv = (float4*)&xs[0][0];
        xsv[t]       = xv[t];
        xsv[t + 256] = xv[t + 256];
    }
    __syncthreads();

    const int cg   = t & 31;
    const int col0 = cg * 4;
    const int rg   = t >> 5;
    const int r0   = rg * 2;

    const float* __restrict__ W  = (m == 0) ? Wq : (m == 1) ? Wk : Wv;
    const float* __restrict__ bb = (m == 0) ? bq : (m == 1) ? bk : bv;
    float* __restrict__ outp     = (m == 0) ? qh : (m == 1) ? kh : vh;

    float4 acc0 = *(const float4*)&bb[col0];
    float4 acc1 = acc0;

    #pragma unroll 4
    for (int k4 = 0; k4 < 32; ++k4) {
        const float4 xa = ((const float4*)xs[r0 + 0])[k4];
        const float4 xb = ((const float4*)xs[r0 + 1])[k4];
        const float4 w0 = *(const float4*)&W[(k4 * 4 + 0) * 128 + col0];
        const float4 w1 = *(const float4*)&W[(k4 * 4 + 1) * 128 + col0];
        const float4 w2 = *(const float4*)&W[(k4 * 4 + 2) * 128 + col0];
        const float4 w3 = *(const float4*)&W[(k4 * 4 + 3) * 128 + col0];
        FMA4(acc0, xa.x, w0); FMA4(acc0, xa.y, w1);
        FMA4(acc0, xa.z, w2); FMA4(acc0, xa.w, w3);
        FMA4(acc1, xb.x, w0); FMA4(acc1, xb.y, w1);
        FMA4(acc1, xb.z, w2); FMA4(acc1, xb.w, w3);
    }

    const float4 th = *(const float4*)&theta[col0];
    const int h    = cg >> 1;
    const int half = cg & 1;

    float4 accs[2] = {acc0, acc1};
    #pragma unroll
    for (int r = 0; r < 2; ++r) {
        float4 c;
        c.x = __cosf(accs[r].x + th.x);
        c.y = __cosf(accs[r].y + th.y);
        c.z = __cosf(accs[r].z + th.z);
        c.w = __cosf(accs[r].w + th.w);
        const float p0 = c.x;
        const float p1 = p0 * c.y;
        const float p2 = p1 * c.z;
        const float p3 = p2 * c.w;
        const float recv = __shfl_xor(p3, 1);
        float4 o;
        if (half == 0) {
            o.x = c.y * c.z * c.w * recv;  // wire 0: c1..c7
            o.y = p1; o.z = p2; o.w = p3;  // wires 1-3: c0..cw
        } else {
            o.x = recv * p0;               // wires 4-7: (c0..c3)*(c4..cw)
            o.y = recv * p1;
            o.z = recv * p2;
            o.w = recv * p3;
        }
        const int g  = row0 + r0 + r;
        const int b_ = g >> 9;
        const int s  = g & 511;
        *(float4*)&outp[(((size_t)b_ * HH + h) * SS + s) * DKK + half * 4] = o;
    }
}

// ---------------------------------------------------------------------------
// Kernel 2: attention. grid 256 = (bh 0..127, q-half 0..1); block 1024 =
// 16 waves; 48KB LDS -> 1 block/CU = 16 waves/CU = 4 waves/SIMD.
// Full K+V (32KB) staged in LDS. Wave wv owns j-slice [wv*32,+32); lane
// owns R=4 q rows (L+64r) of the block's 256-row q-half. q pre-scaled by
// log2(e)/sqrt(8) -> exp2f (native). Single-pass softmax (bounded scores:
// |s| <= 4.1). ALL j-combining stays in LDS: 4 slots [4][256][3]f4 (48KB,
// unioned with the dead stage); waves 4-7 / 8-11 / 12-15 accumulate into
// slots 0-3 in 3 phases; final 4-way reduce + normalize -> hid row-major.
// No global partials (R11 lesson: 67MB write amplification).
// ---------------------------------------------------------------------------
__global__ __launch_bounds__(1024, 4) void k_attn(
    const float* __restrict__ qh, const float* __restrict__ kh,
    const float* __restrict__ vh, float* __restrict__ hid)
{
    __shared__ float4 smem[3072];     // 48KB: stage (2048 f4) / combine (3072)

    const int t  = threadIdx.x;       // 0..1023
    const int L  = t & 63;
    const int wv = t >> 6;            // 0..15
    const int bh = blockIdx.x & 127;
    const int q0 = (blockIdx.x >> 7) * 256;

    // stage K/V (2048 f4; 2 per thread, coalesced)
    {
        const float4* kg = (const float4*)kh + (size_t)bh * 1024;
        const float4* vg = (const float4*)vh + (size_t)bh * 1024;
        smem[t]        = kg[t];
        smem[1024 + t] = vg[t];
    }

    // lane's 4 q rows, pre-scaled so exp2f(s) == exp(q.k/sqrt(8))
    const float sc = 0.51012091944f;  // log2(e)/sqrt(8)
    float4 qa[4], qb[4];
    {
        const float4* qg = (const float4*)qh + ((size_t)bh * 512 + q0) * 2;
        #pragma unroll
        for (int r = 0; r < 4; ++r) {
            float4 a = qg[(L + 64 * r) * 2];
            float4 b = qg[(L + 64 * r) * 2 + 1];
            a.x *= sc; a.y *= sc; a.z *= sc; a.w *= sc;
            b.x *= sc; b.y *= sc; b.z *= sc; b.w *= sc;
            qa[r] = a; qb[r] = b;
        }
    }
    __syncthreads();

    float4 aA[4], aB[4];
    float  den[4];
    #pragma unroll
    for (int r = 0; r < 4; ++r) {
        aA[r] = make_float4(0.f, 0.f, 0.f, 0.f);
        aB[r] = make_float4(0.f, 0.f, 0.f, 0.f);
        den[r] = 0.f;
    }

    const float4* kbase = smem + wv * 64;          // 32 rows x 2 f4
    const float4* vbase = smem + 1024 + wv * 64;

    #pragma unroll 4
    for (int j = 0; j < 32; ++j) {
        const float4 k0 = kbase[2 * j];
        const float4 k1 = kbase[2 * j + 1];
        const float4 v0 = vbase[2 * j];
        const float4 v1 = vbase[2 * j + 1];
        #pragma unroll
        for (int r = 0; r < 4; ++r) {
            const float s = DOT4(qa[r], k0) + DOT4(qb[r], k1);
            const float e = exp2f(s);
            den[r] += e;
            FMA4(aA[r], e, v0);
            FMA4(aB[r], e, v1);
        }
    }
    __syncthreads();    // all 16 waves done reading the stage

    // combine: slots [4][256][3] f4; waves 0-3 write, 4-7/8-11/12-15 add
    if (wv < 4) {
        #pragma unroll
        for (int r = 0; r < 4; ++r) {
            const int idx = (wv * 256 + L + 64 * r) * 3;
            smem[idx]     = aA[r];
            smem[idx + 1] = aB[r];
            smem[idx + 2] = make_float4(den[r], 0.f, 0.f, 0.f);
        }
    }
    __syncthreads();
    #pragma unroll
    for (int grp = 1; grp < 4; ++grp) {
        if ((wv >> 2) == grp) {
            const int slot = wv & 3;
            #pragma unroll
            for (int r = 0; r < 4; ++r) {
                const int idx = (slot * 256 + L + 64 * r) * 3;
                float4 pa = smem[idx];
                float4 pb = smem[idx + 1];
                float4 pd = smem[idx + 2];
                ADD4(pa, aA[r]); ADD4(pb, aB[r]); pd.x += den[r];
                smem[idx]     = pa;
                smem[idx + 1] = pb;
                smem[idx + 2] = pd;
            }
        }
        __syncthreads();
    }

    // final 4-way reduce + normalize + write (row-major hid)
    if (t < 256) {
        float4 rA = make_float4(0.f, 0.f, 0.f, 0.f), rB = rA;
        float rd = 0.f;
        #pragma unroll
        for (int s4 = 0; s4 < 4; ++s4) {
            const int idx = (s4 * 256 + t) * 3;
            const float4 a = smem[idx];
            const float4 b = smem[idx + 1];
            ADD4(rA, a); ADD4(rB, b);
            rd += smem[idx + 2].x;
        }
        const float inv = 1.0f / rd;
        rA.x *= inv; rA.y *= inv; rA.z *= inv; rA.w *= inv;
        rB.x *= inv; rB.y *= inv; rB.z *= inv; rB.w *= inv;
        const int b_ = bh >> 4, h = bh & 15;
        float* o = hid + ((size_t)(b_ * 512) + q0 + t) * 128 + h * 8;
        ((float4*)o)[0] = rA;
        ((float4*)o)[1] = rB;
    }
}

// ---------------------------------------------------------------------------
// Kernel 3: output projection hid(4096x128, row-major) @ Wo(128x128) + bo.
// grid 256 x 256: 16 rows/block, LDS stage, per-lane tile 2 rows x 4 cols.
// ---------------------------------------------------------------------------
__global__ __launch_bounds__(256, 4) void k_out(
    const float* __restrict__ hid, const float* __restrict__ Wo,
    const float* __restrict__ bo, float* __restrict__ out)
{
    __shared__ float hs[16][128];
    const int t = threadIdx.x;
    const int row0 = blockIdx.x * 16;

    {
        const float4* hv = (const float4*)(hid + (size_t)row0 * 128);
        float4* hsv = (float4*)&hs[0][0];
        hsv[t]       = hv[t];
        hsv[t + 256] = hv[t + 256];
    }
    __syncthreads();

    const int cg   = t & 31;
    const int col0 = cg * 4;
    const int rg   = t >> 5;
    const int r0   = rg * 2;

    float4 acc0 = *(const float4*)&bo[col0];
    float4 acc1 = acc0;

    #pragma unroll 4
    for (int k4 = 0; k4 < 32; ++k4) {
        const float4 xa = ((const float4*)hs[r0 + 0])[k4];
        const float4 xb = ((const float4*)hs[r0 + 1])[k4];
        const float4 w0 = *(const float4*)&Wo[(k4 * 4 + 0) * 128 + col0];
        const float4 w1 = *(const float4*)&Wo[(k4 * 4 + 1) * 128 + col0];
        const float4 w2 = *(const float4*)&Wo[(k4 * 4 + 2) * 128 + col0];
        const float4 w3 = *(const float4*)&Wo[(k4 * 4 + 3) * 128 + col0];
        FMA4(acc0, xa.x, w0); FMA4(acc0, xa.y, w1);
        FMA4(acc0, xa.z, w2); FMA4(acc0, xa.w, w3);
        FMA4(acc1, xb.x, w0); FMA4(acc1, xb.y, w1);
        FMA4(acc1, xb.z, w2); FMA4(acc1, xb.w, w3);
    }

    *(float4*)&out[(size_t)(row0 + r0 + 0) * 128 + col0] = acc0;
    *(float4*)&out[(size_t)(row0 + r0 + 1) * 128 + col0] = acc1;
}

// ---------------------------------------------------------------------------
extern "C" void kernel_launch(void* const* d_in, const int* in_sizes, int n_in,
                              void* d_out, int out_size, void* d_ws, size_t ws_size,
                              hipStream_t stream)
{
    const float* x     = (const float*)d_in[0];
    const float* Wq    = (const float*)d_in[1];
    const float* bq    = (const float*)d_in[2];
    const float* Wk    = (const float*)d_in[3];
    const float* bk    = (const float*)d_in[4];
    const float* Wv    = (const float*)d_in[5];
    const float* bv    = (const float*)d_in[6];
    const float* Wo    = (const float*)d_in[7];
    const float* bo    = (const float*)d_in[8];
    const float* theta = (const float*)d_in[9];
    float* out = (float*)d_out;

    float* ws  = (float*)d_ws;
    float* qh  = ws;                   // B*H*S*8 = 524288 floats each
    float* kh  = ws + 524288;
    float* vh  = ws + 1048576;
    float* hid = ws + 1572864;         // row-major (B,S,E)

    k_qkvq<<<dim3(256, 3), 256, 0, stream>>>(x, Wq, bq, Wk, bk, Wv, bv,
                                             theta, qh, kh, vh);
    k_attn<<<256, 1024, 0, stream>>>(qh, kh, vh, hid);
    k_out <<<256, 256, 0, stream>>>(hid, Wo, bo, out);
}

// Round 13
// 47.763 us; speedup vs baseline: 1.3886x; 1.3886x over previous
//
#include <hip/hip_runtime.h>
#include <hip/hip_bf16.h>
#include <math.h>

#define BB 8
#define SS 512
#define EE 128
#define HH 16
#define DKK 8

#define FMA4(ACC, S, W) do { (ACC).x += (S)*(W).x; (ACC).y += (S)*(W).y; \
                             (ACC).z += (S)*(W).z; (ACC).w += (S)*(W).w; } while(0)
#define ADD4(A, B) do { (A).x += (B).x; (A).y += (B).y; (A).z += (B).z; (A).w += (B).w; } while(0)
#define DOT4(A, B) ((A).x*(B).x + (A).y*(B).y + (A).z*(B).z + (A).w*(B).w)

// ---------------------------------------------------------------------------
// Kernel 1: QKV GEMM + bias + theta + quantum head (R9-proven, unchanged).
// grid (256, 3); block 256 = 4 waves; per-lane tile 2 rows x 4 cols.
// x tile staged in LDS (8KB, broadcast b128 reads); W coalesced float4.
// Output layout (B, H, S, 8). Live state ~45 regs -> no spill at 64-VGPR cap.
// ---------------------------------------------------------------------------
__global__ __launch_bounds__(256, 4) void k_qkvq(
    const float* __restrict__ x,
    const float* __restrict__ Wq, const float* __restrict__ bq,
    const float* __restrict__ Wk, const float* __restrict__ bk,
    const float* __restrict__ Wv, const float* __restrict__ bv,
    const float* __restrict__ theta,
    float* __restrict__ qh, float* __restrict__ kh, float* __restrict__ vh)
{
    __shared__ float xs[16][128];
    const int t = threadIdx.x;
    const int m = blockIdx.y;
    const int row0 = blockIdx.x * 16;

    {
        const float4* xv = (const float4*)(x + (size_t)row0 * 128);
        float4* xsv = (float4*)&xs[0][0];
        xsv[t]       = xv[t];
        xsv[t + 256] = xv[t + 256];
    }
    __syncthreads();

    const int cg   = t & 31;
    const int col0 = cg * 4;
    const int rg   = t >> 5;
    const int r0   = rg * 2;

    const float* __restrict__ W  = (m == 0) ? Wq : (m == 1) ? Wk : Wv;
    const float* __restrict__ bb = (m == 0) ? bq : (m == 1) ? bk : bv;
    float* __restrict__ outp     = (m == 0) ? qh : (m == 1) ? kh : vh;

    float4 acc0 = *(const float4*)&bb[col0];
    float4 acc1 = acc0;

    #pragma unroll 4
    for (int k4 = 0; k4 < 32; ++k4) {
        const float4 xa = ((const float4*)xs[r0 + 0])[k4];
        const float4 xb = ((const float4*)xs[r0 + 1])[k4];
        const float4 w0 = *(const float4*)&W[(k4 * 4 + 0) * 128 + col0];
        const float4 w1 = *(const float4*)&W[(k4 * 4 + 1) * 128 + col0];
        const float4 w2 = *(const float4*)&W[(k4 * 4 + 2) * 128 + col0];
        const float4 w3 = *(const float4*)&W[(k4 * 4 + 3) * 128 + col0];
        FMA4(acc0, xa.x, w0); FMA4(acc0, xa.y, w1);
        FMA4(acc0, xa.z, w2); FMA4(acc0, xa.w, w3);
        FMA4(acc1, xb.x, w0); FMA4(acc1, xb.y, w1);
        FMA4(acc1, xb.z, w2); FMA4(acc1, xb.w, w3);
    }

    const float4 th = *(const float4*)&theta[col0];
    const int h    = cg >> 1;
    const int half = cg & 1;

    float4 accs[2] = {acc0, acc1};
    #pragma unroll
    for (int r = 0; r < 2; ++r) {
        float4 c;
        c.x = __cosf(accs[r].x + th.x);
        c.y = __cosf(accs[r].y + th.y);
        c.z = __cosf(accs[r].z + th.z);
        c.w = __cosf(accs[r].w + th.w);
        const float p0 = c.x;
        const float p1 = p0 * c.y;
        const float p2 = p1 * c.z;
        const float p3 = p2 * c.w;
        const float recv = __shfl_xor(p3, 1);
        float4 o;
        if (half == 0) {
            o.x = c.y * c.z * c.w * recv;  // wire 0: c1..c7
            o.y = p1; o.z = p2; o.w = p3;  // wires 1-3: c0..cw
        } else {
            o.x = recv * p0;               // wires 4-7: (c0..c3)*(c4..cw)
            o.y = recv * p1;
            o.z = recv * p2;
            o.w = recv * p3;
        }
        const int g  = row0 + r0 + r;
        const int b_ = g >> 9;
        const int s  = g & 511;
        *(float4*)&outp[(((size_t)b_ * HH + h) * SS + s) * DKK + half * 4] = o;
    }
}

// ---------------------------------------------------------------------------
// Kernel 2: attention (R9 structure + SPILL FIX).
// grid 256 = (bh 0..127) x (q-half 0..1): one block per CU, all CUs busy.
// block 512 = 8 waves; __launch_bounds__(512, 2) -> VGPR cap >= 128 under
// either HIP occupancy-arg semantics; live state ~95 regs -> NO scratch
// spill (R9-R12 were silently spilling ~30 regs at the 64-VGPR tier ->
// ~70MB HBM write traffic per dispatch -> 50us).
// Full K+V (32KB) staged in LDS; wave wv = j-slice [wv*64,+64); lane owns
// R=4 q rows (L+64r). q pre-scaled by log2(e)/sqrt(8) -> exp2f. Single-pass
// softmax (bounded scores). In-LDS combine (48KB union with dead stage);
// normalize; row-major hid write.
// ---------------------------------------------------------------------------
__global__ __launch_bounds__(512, 2) void k_attn(
    const float* __restrict__ qh, const float* __restrict__ kh,
    const float* __restrict__ vh, float* __restrict__ hid)
{
    __shared__ float4 smem[3072];     // 48KB: stage (2048 f4) / combine (3072)

    const int t  = threadIdx.x;       // 0..511
    const int L  = t & 63;
    const int wv = t >> 6;            // 0..7
    const int bh = blockIdx.x & 127;
    const int q0 = (blockIdx.x >> 7) * 256;   // 0 or 256

    // stage K/V (2048 f4; 4 per thread, coalesced)
    {
        const float4* kg = (const float4*)kh + (size_t)bh * 1024;
        const float4* vg = (const float4*)vh + (size_t)bh * 1024;
        smem[t]        = kg[t];
        smem[t + 512]  = kg[t + 512];
        smem[1024 + t] = vg[t];
        smem[1536 + t] = vg[t + 512];
    }

    // lane's 4 q rows, pre-scaled so exp2f(s) == exp(q.k/sqrt(8))
    const float sc = 0.51012091944f;  // log2(e)/sqrt(8)
    float4 qa[4], qb[4];
    {
        const float4* qg = (const float4*)qh + ((size_t)bh * 512 + q0) * 2;
        #pragma unroll
        for (int r = 0; r < 4; ++r) {
            float4 a = qg[(L + 64 * r) * 2];
            float4 b = qg[(L + 64 * r) * 2 + 1];
            a.x *= sc; a.y *= sc; a.z *= sc; a.w *= sc;
            b.x *= sc; b.y *= sc; b.z *= sc; b.w *= sc;
            qa[r] = a; qb[r] = b;
        }
    }
    __syncthreads();

    float4 aA[4], aB[4];
    float  den[4];
    #pragma unroll
    for (int r = 0; r < 4; ++r) {
        aA[r] = make_float4(0.f, 0.f, 0.f, 0.f);
        aB[r] = make_float4(0.f, 0.f, 0.f, 0.f);
        den[r] = 0.f;
    }

    const float4* kbase = smem + wv * 128;          // this wave's 64 j rows
    const float4* vbase = smem + 1024 + wv * 128;

    #pragma unroll 4
    for (int j = 0; j < 64; ++j) {
        const float4 k0 = kbase[2 * j];
        const float4 k1 = kbase[2 * j + 1];
        const float4 v0 = vbase[2 * j];
        const float4 v1 = vbase[2 * j + 1];
        #pragma unroll
        for (int r = 0; r < 4; ++r) {
            const float s = DOT4(qa[r], k0) + DOT4(qb[r], k1);
            const float e = exp2f(s);
            den[r] += e;
            FMA4(aA[r], e, v0);
            FMA4(aB[r], e, v1);
        }
    }
    __syncthreads();    // all waves done reading the stage

    // combine: slots [4][256][3] f4 (48KB); waves 0-3 write, 4-7 add
    if (wv < 4) {
        #pragma unroll
        for (int r = 0; r < 4; ++r) {
            const int idx = (wv * 256 + L + 64 * r) * 3;
            smem[idx]     = aA[r];
            smem[idx + 1] = aB[r];
            smem[idx + 2] = make_float4(den[r], 0.f, 0.f, 0.f);
        }
    }
    __syncthreads();
    if (wv >= 4) {
        #pragma unroll
        for (int r = 0; r < 4; ++r) {
            const int idx = ((wv - 4) * 256 + L + 64 * r) * 3;
            float4 pa = smem[idx];
            float4 pb = smem[idx + 1];
            float4 pd = smem[idx + 2];
            ADD4(pa, aA[r]); ADD4(pb, aB[r]); pd.x += den[r];
            smem[idx]     = pa;
            smem[idx + 1] = pb;
            smem[idx + 2] = pd;
        }
    }
    __syncthreads();

    // final 4-way reduce + normalize + write (row-major hid)
    if (t < 256) {
        float4 rA = make_float4(0.f, 0.f, 0.f, 0.f), rB = rA;
        float rd = 0.f;
        #pragma unroll
        for (int s4 = 0; s4 < 4; ++s4) {
            const int idx = (s4 * 256 + t) * 3;
            const float4 a = smem[idx];
            const float4 b = smem[idx + 1];
            ADD4(rA, a); ADD4(rB, b);
            rd += smem[idx + 2].x;
        }
        const float inv = 1.0f / rd;
        rA.x *= inv; rA.y *= inv; rA.z *= inv; rA.w *= inv;
        rB.x *= inv; rB.y *= inv; rB.z *= inv; rB.w *= inv;
        const int b_ = bh >> 4, h = bh & 15;
        float* o = hid + ((size_t)(b_ * 512) + q0 + t) * 128 + h * 8;
        ((float4*)o)[0] = rA;
        ((float4*)o)[1] = rB;
    }
}

// ---------------------------------------------------------------------------
// Kernel 3: output projection hid(4096x128, row-major) @ Wo(128x128) + bo.
// grid 256 x 256: 16 rows/block (unchanged, no spill: ~35 live regs).
// ---------------------------------------------------------------------------
__global__ __launch_bounds__(256, 4) void k_out(
    const float* __restrict__ hid, const float* __restrict__ Wo,
    const float* __restrict__ bo, float* __restrict__ out)
{
    __shared__ float hs[16][128];
    const int t = threadIdx.x;
    const int row0 = blockIdx.x * 16;

    {
        const float4* hv = (const float4*)(hid + (size_t)row0 * 128);
        float4* hsv = (float4*)&hs[0][0];
        hsv[t]       = hv[t];
        hsv[t + 256] = hv[t + 256];
    }
    __syncthreads();

    const int cg   = t & 31;
    const int col0 = cg * 4;
    const int rg   = t >> 5;
    const int r0   = rg * 2;

    float4 acc0 = *(const float4*)&bo[col0];
    float4 acc1 = acc0;

    #pragma unroll 4
    for (int k4 = 0; k4 < 32; ++k4) {
        const float4 xa = ((const float4*)hs[r0 + 0])[k4];
        const float4 xb = ((const float4*)hs[r0 + 1])[k4];
        const float4 w0 = *(const float4*)&Wo[(k4 * 4 + 0) * 128 + col0];
        const float4 w1 = *(const float4*)&Wo[(k4 * 4 + 1) * 128 + col0];
        const float4 w2 = *(const float4*)&Wo[(k4 * 4 + 2) * 128 + col0];
        const float4 w3 = *(const float4*)&Wo[(k4 * 4 + 3) * 128 + col0];
        FMA4(acc0, xa.x, w0); FMA4(acc0, xa.y, w1);
        FMA4(acc0, xa.z, w2); FMA4(acc0, xa.w, w3);
        FMA4(acc1, xb.x, w0); FMA4(acc1, xb.y, w1);
        FMA4(acc1, xb.z, w2); FMA4(acc1, xb.w, w3);
    }

    *(float4*)&out[(size_t)(row0 + r0 + 0) * 128 + col0] = acc0;
    *(float4*)&out[(size_t)(row0 + r0 + 1) * 128 + col0] = acc1;
}

// ---------------------------------------------------------------------------
extern "C" void kernel_launch(void* const* d_in, const int* in_sizes, int n_in,
                              void* d_out, int out_size, void* d_ws, size_t ws_size,
                              hipStream_t stream)
{
    const float* x     = (const float*)d_in[0];
    const float* Wq    = (const float*)d_in[1];
    const float* bq    = (const float*)d_in[2];
    const float* Wk    = (const float*)d_in[3];
    const float* bk    = (const float*)d_in[4];
    const float* Wv    = (const float*)d_in[5];
    const float* bv    = (const float*)d_in[6];
    const float* Wo    = (const float*)d_in[7];
    const float* bo    = (const float*)d_in[8];
    const float* theta = (const float*)d_in[9];
    float* out = (float*)d_out;

    float* ws  = (float*)d_ws;
    float* qh  = ws;                   // B*H*S*8 = 524288 floats each
    float* kh  = ws + 524288;
    float* vh  = ws + 1048576;
    float* hid = ws + 1572864;         // row-major (B,S,E)

    k_qkvq<<<dim3(256, 3), 256, 0, stream>>>(x, Wq, bq, Wk, bk, Wv, bv,
                                             theta, qh, kh, vh);
    k_attn<<<256, 512, 0, stream>>>(qh, kh, vh, hid);
    k_out <<<256, 256, 0, stream>>>(hid, Wo, bo, out);
}